// Round 1
// baseline (1739.543 us; speedup 1.0000x reference)
//
#include <hip/hip_runtime.h>

#define M 128
#define BT 64  // one wave per block; each thread owns LDS column tid

// CSR tables: for each target node j, the list of sources i with li[i]==j (resp ri).
struct Tables {
  float sp[M];      // sigmoid(split_points_param*4-2)
  float vals[M];    // tile(values_param*3+1, 4)
  int Loff[M + 1];
  int Roff[M + 1];
  int Lidx[M];
  int Ridx[M];
};

__device__ Tables g_tb;

__global__ void setup_kernel(const float* __restrict__ spp,
                             const float* __restrict__ vp,
                             const float* __restrict__ Lm,
                             const float* __restrict__ Rm) {
  __shared__ int sli[M], sri[M], scl[M], scr[M], sofL[M + 1], sofR[M + 1];
  const int i = threadIdx.x;
  if (i < M) {
    g_tb.sp[i] = 1.f / (1.f + __expf(2.f - 4.f * spp[i]));
    g_tb.vals[i] = vp[i & 31] * 3.f + 1.f;
    // find the one-hot column of row i in each matrix
    int l = 0, r = 0;
    for (int j = 0; j < M; ++j) {
      if (Lm[i * M + j] > 0.5f) l = j;
      if (Rm[i * M + j] > 0.5f) r = j;
    }
    sli[i] = l;
    sri[i] = r;
  }
  __syncthreads();
  if (i < M) {
    int a = 0, b = 0;
    for (int k = 0; k < M; ++k) {
      a += (sli[k] == i);
      b += (sri[k] == i);
    }
    scl[i] = a;
    scr[i] = b;
  }
  __syncthreads();
  if (i == 0) {
    int s0 = 0, s1 = 0;
    for (int j = 0; j < M; ++j) {
      sofL[j] = s0; s0 += scl[j];
      sofR[j] = s1; s1 += scr[j];
    }
    sofL[M] = s0;
    sofR[M] = s1;
  }
  __syncthreads();
  if (i < M) {
    g_tb.Loff[i] = sofL[i];
    g_tb.Roff[i] = sofR[i];
    if (i == 0) { g_tb.Loff[M] = sofL[M]; g_tb.Roff[M] = sofR[M]; }
    int pl = sofL[i], pr = sofR[i];
    for (int k = 0; k < M; ++k) {
      if (sli[k] == i) g_tb.Lidx[pl++] = k;
      if (sri[k] == i) g_tb.Ridx[pr++] = k;
    }
  }
}

__launch_bounds__(BT)
__global__ void fractal_kernel(const float* __restrict__ x,
                               const int* __restrict__ dpt,
                               float* __restrict__ out, int n) {
  // [buffer][node][tid] — wave-uniform node index => conflict-free (2-way aliasing is free)
  __shared__ float w[2][M][BT];
  const int tid = threadIdx.x;
  const int gid = blockIdx.x * BT + tid;
  const float xv = (gid < n) ? x[gid] : 0.5f;
  const int depth = dpt[0];

  // w0 is one-hot at node 0
#pragma unroll
  for (int j = 0; j < M; ++j) w[0][j][tid] = (j == 0) ? 1.f : 0.f;

  if (depth < 1) {
    if (gid < n) out[gid] = g_tb.vals[0];
    return;
  }

  float dot = g_tb.sp[0];  // w0 . sp
  float lo = 0.f, hi = 1.f;
  int cur = 0;

  for (int k = 0; k < depth - 1; ++k) {
    const float s = lo + dot * (hi - lo);
    const float t = 1.f / (1.f + __expf((s - xv) * 10.f));
    const float u = 1.f - t;
    float acc = 0.f;
#pragma unroll 4
    for (int j = 0; j < M; ++j) {
      float aL = 0.f, aR = 0.f;
      int b = g_tb.Loff[j], e = g_tb.Loff[j + 1];
      for (int m = b; m < e; ++m) aL += w[cur][g_tb.Lidx[m]][tid];
      b = g_tb.Roff[j]; e = g_tb.Roff[j + 1];
      for (int m = b; m < e; ++m) aR += w[cur][g_tb.Ridx[m]][tid];
      const float nv = u * aL + t * aR;
      w[cur ^ 1][j][tid] = nv;
      acc += nv * g_tb.sp[j];  // fused next-iteration dot product
    }
    dot = acc;
    const float nlo = u * lo + t * s;
    const float nhi = u * s + t * hi;
    lo = nlo;
    hi = nhi;
    cur ^= 1;
  }

  // final depth step: gather + fused (w . values), no write-back needed
  {
    const float s = lo + dot * (hi - lo);
    const float t = 1.f / (1.f + __expf((s - xv) * 10.f));
    const float u = 1.f - t;
    float acc = 0.f;
#pragma unroll 4
    for (int j = 0; j < M; ++j) {
      float aL = 0.f, aR = 0.f;
      int b = g_tb.Loff[j], e = g_tb.Loff[j + 1];
      for (int m = b; m < e; ++m) aL += w[cur][g_tb.Lidx[m]][tid];
      b = g_tb.Roff[j]; e = g_tb.Roff[j + 1];
      for (int m = b; m < e; ++m) aR += w[cur][g_tb.Ridx[m]][tid];
      acc += (u * aL + t * aR) * g_tb.vals[j];
    }
    if (gid < n) out[gid] = acc;
  }
}

extern "C" void kernel_launch(void* const* d_in, const int* in_sizes, int n_in,
                              void* d_out, int out_size, void* d_ws, size_t ws_size,
                              hipStream_t stream) {
  const float* x   = (const float*)d_in[0];
  const float* spp = (const float*)d_in[1];
  const float* vp  = (const float*)d_in[2];
  const float* Lm  = (const float*)d_in[3];
  const float* Rm  = (const float*)d_in[4];
  const int* dpt   = (const int*)d_in[5];
  float* out = (float*)d_out;
  const int n = in_sizes[0];

  hipLaunchKernelGGL(setup_kernel, dim3(1), dim3(M), 0, stream, spp, vp, Lm, Rm);
  const int blocks = (n + BT - 1) / BT;
  hipLaunchKernelGGL(fractal_kernel, dim3(blocks), dim3(BT), 0, stream,
                     x, dpt, out, n);
}

// Round 2
// 28.352 us; speedup vs baseline: 61.3561x; 61.3561x over previous
//
#include <hip/hip_runtime.h>

#define M 128
#define BT 64

// Path tables (shared by all points), rebuilt by setup_kernel every launch:
//   g_T[2^d + i] = sp[node_d(i)]   (d = 0..9)   -- used for dot_{d+1}
//   g_V[2^d + i] = vals[node_d(i)] (d = 0..10)  -- used for the output contraction
// where node_d(i) follows the path bits of i (MSB = first step; left=li, right=ri).
__device__ float g_T[1024];
__device__ float g_V[2048];
__device__ float g_sp[M], g_vals[M];
__device__ int   g_li[M], g_ri[M];

__global__ void setup_kernel(const float* __restrict__ spp,
                             const float* __restrict__ vp,
                             const float* __restrict__ Lm,
                             const float* __restrict__ Rm) {
  __shared__ float ssp[M], svl[M];
  __shared__ int sli[M], sri[M];
  __shared__ int cur[1024], nxt[1024];
  const int t = threadIdx.x;  // 256 threads
  if (t < M) {
    ssp[t] = 1.f / (1.f + __expf(2.f - 4.f * spp[t]));
    svl[t] = vp[t & 31] * 3.f + 1.f;
  }
  {
    // one-hot column scan: threads 0..127 -> Lm rows, 128..255 -> Rm rows
    const int row = t & (M - 1);
    const float* Mt = (t < M) ? Lm : Rm;
    const float4* r4 = (const float4*)(Mt + row * M);
    int idx = 0;
#pragma unroll
    for (int j4 = 0; j4 < M / 4; ++j4) {
      const float4 v = r4[j4];
      if (v.x > 0.5f) idx = 4 * j4;
      if (v.y > 0.5f) idx = 4 * j4 + 1;
      if (v.z > 0.5f) idx = 4 * j4 + 2;
      if (v.w > 0.5f) idx = 4 * j4 + 3;
    }
    if (t < M) sli[row] = idx; else sri[row] = idx;
  }
  __syncthreads();
  if (t < M) {
    g_sp[t] = ssp[t];
    g_vals[t] = svl[t];
    g_li[t] = sli[t];
    g_ri[t] = sri[t];
  }
  if (t == 0) cur[0] = 0;
  __syncthreads();
  int S = 1;
  for (int d = 0; d <= 10; ++d) {
    for (int i = t; i < S; i += 256) {
      const int nd = cur[i];
      g_V[S + i] = svl[nd];
      if (d <= 9) g_T[S + i] = ssp[nd];
      if (d < 10) { nxt[2 * i] = sli[nd]; nxt[2 * i + 1] = sri[nd]; }
    }
    __syncthreads();
    if (d < 10) {
      for (int i = t; i < 2 * S; i += 256) cur[i] = nxt[i];
      __syncthreads();
    }
    S <<= 1;
  }
}

// one prefix step: dot from T_{k-1} (size S at offset S), then grow c (S -> 2S)
#define PSTEP(S)                                                              \
  {                                                                           \
    float dot = 0.f;                                                          \
    _Pragma("unroll") for (int i = 0; i < (S); ++i)                           \
        dot = fmaf(c[i], sT[(S) + i], dot);                                   \
    const float sv = lo + dot * (hi - lo);                                    \
    const float tt = 1.f / (1.f + __expf((sv - xv) * 10.f));                  \
    const float uu = 1.f - tt;                                                \
    const float nlo = fmaf(tt, sv, uu * lo);                                  \
    const float nhi = fmaf(tt, hi, uu * sv);                                  \
    lo = nlo; hi = nhi;                                                       \
    _Pragma("unroll") for (int i = (S)-1; i >= 0; --i) {                      \
      const float v = c[i];                                                   \
      c[2 * i + 1] = v * tt;                                                  \
      c[2 * i] = v * uu;                                                      \
    }                                                                         \
  }

// suffix tail: sigmoid + interval update + grow W (SW -> 2*SW)
#define SSTEP_TAIL(SW, dot)                                                   \
  {                                                                           \
    const float sv = lo + (dot) * (hi - lo);                                  \
    const float tt = 1.f / (1.f + __expf((sv - xv) * 10.f));                  \
    const float uu = 1.f - tt;                                                \
    const float nlo = fmaf(tt, sv, uu * lo);                                  \
    const float nhi = fmaf(tt, hi, uu * sv);                                  \
    lo = nlo; hi = nhi;                                                       \
    _Pragma("unroll") for (int s2 = (SW)-1; s2 >= 0; --s2) {                  \
      const float v = W[s2];                                                  \
      W[2 * s2 + 1] = v * tt;                                                 \
      W[2 * s2] = v * uu;                                                     \
    }                                                                         \
  }

__launch_bounds__(BT)
__global__ void fractal_fast(const float* __restrict__ x,
                             const int* __restrict__ dpt,
                             float* __restrict__ out, int n) {
  __shared__ __align__(16) float sT[1024];
  __shared__ __align__(16) float sV[2048];
  const int tid = threadIdx.x;
#pragma unroll
  for (int i = 0; i < 16; ++i) sT[tid + i * BT] = g_T[tid + i * BT];
#pragma unroll
  for (int i = 0; i < 32; ++i) sV[tid + i * BT] = g_V[tid + i * BT];
  __syncthreads();

  const int gid = blockIdx.x * BT + tid;
  const float xv = (gid < n) ? x[gid] : 0.5f;
  const int depth = dpt[0];
  float outv;

  if (depth == 10) {
    float c[64], W[16];
    float lo = 0.f, hi = 1.f;
    c[0] = 1.f;
    PSTEP(1) PSTEP(2) PSTEP(4) PSTEP(8) PSTEP(16) PSTEP(32)
    W[0] = 1.f;
    {  // k = 7: T_6 at sT[64], SW = 1
      float dot = 0.f;
#pragma unroll
      for (int g = 0; g < 16; ++g) {
        const float4 tv = *(const float4*)&sT[64 + 4 * g];
        dot = fmaf(c[4 * g], tv.x, dot);
        dot = fmaf(c[4 * g + 1], tv.y, dot);
        dot = fmaf(c[4 * g + 2], tv.z, dot);
        dot = fmaf(c[4 * g + 3], tv.w, dot);
      }
      SSTEP_TAIL(1, dot)
    }
    {  // k = 8: T_7 at sT[128], SW = 2
      float dot = 0.f;
#pragma unroll
      for (int g = 0; g < 32; ++g) {
        const float4 tv = *(const float4*)&sT[128 + 4 * g];
        dot = fmaf(c[2 * g], fmaf(W[0], tv.x, W[1] * tv.y), dot);
        dot = fmaf(c[2 * g + 1], fmaf(W[0], tv.z, W[1] * tv.w), dot);
      }
      SSTEP_TAIL(2, dot)
    }
    {  // k = 9: T_8 at sT[256], SW = 4
      float dot = 0.f;
#pragma unroll
      for (int i = 0; i < 64; ++i) {
        const float4 tv = *(const float4*)&sT[256 + 4 * i];
        float a = W[0] * tv.x;
        a = fmaf(W[1], tv.y, a);
        a = fmaf(W[2], tv.z, a);
        a = fmaf(W[3], tv.w, a);
        dot = fmaf(c[i], a, dot);
      }
      SSTEP_TAIL(4, dot)
    }
    {  // k = 10: T_9 at sT[512], SW = 8
      float dot = 0.f;
#pragma unroll
      for (int i = 0; i < 64; ++i) {
        const float4 ta = *(const float4*)&sT[512 + 8 * i];
        const float4 tb = *(const float4*)&sT[512 + 8 * i + 4];
        float a = W[0] * ta.x;
        a = fmaf(W[1], ta.y, a);
        a = fmaf(W[2], ta.z, a);
        a = fmaf(W[3], ta.w, a);
        a = fmaf(W[4], tb.x, a);
        a = fmaf(W[5], tb.y, a);
        a = fmaf(W[6], tb.z, a);
        a = fmaf(W[7], tb.w, a);
        dot = fmaf(c[i], a, dot);
      }
      SSTEP_TAIL(8, dot)
    }
    {  // output: V_10 at sV[1024], SW = 16
      float acc = 0.f;
#pragma unroll
      for (int i = 0; i < 64; ++i) {
        const float4 va = *(const float4*)&sV[1024 + 16 * i];
        const float4 vb = *(const float4*)&sV[1024 + 16 * i + 4];
        const float4 vc = *(const float4*)&sV[1024 + 16 * i + 8];
        const float4 vd = *(const float4*)&sV[1024 + 16 * i + 12];
        float a = W[0] * va.x;
        a = fmaf(W[1], va.y, a);
        a = fmaf(W[2], va.z, a);
        a = fmaf(W[3], va.w, a);
        a = fmaf(W[4], vb.x, a);
        a = fmaf(W[5], vb.y, a);
        a = fmaf(W[6], vb.z, a);
        a = fmaf(W[7], vb.w, a);
        a = fmaf(W[8], vc.x, a);
        a = fmaf(W[9], vc.y, a);
        a = fmaf(W[10], vc.z, a);
        a = fmaf(W[11], vc.w, a);
        a = fmaf(W[12], vd.x, a);
        a = fmaf(W[13], vd.y, a);
        a = fmaf(W[14], vd.z, a);
        a = fmaf(W[15], vd.w, a);
        acc = fmaf(c[i], a, acc);
      }
      outv = acc;
    }
  } else {
    // generic-depth fallback (never taken in the bench; scratch-backed, correct)
    float w0[M], w1[M];
    for (int j = 0; j < M; ++j) w0[j] = 0.f;
    w0[0] = 1.f;
    float lo = 0.f, hi = 1.f;
    float* wc = w0;
    float* wn = w1;
    for (int k = 0; k < depth; ++k) {
      float dot = 0.f;
      for (int j = 0; j < M; ++j) dot += wc[j] * g_sp[j];
      const float sv = lo + dot * (hi - lo);
      const float tt = 1.f / (1.f + __expf((sv - xv) * 10.f));
      const float uu = 1.f - tt;
      for (int j = 0; j < M; ++j) wn[j] = 0.f;
      for (int j = 0; j < M; ++j) {
        wn[g_li[j]] += uu * wc[j];
        wn[g_ri[j]] += tt * wc[j];
      }
      const float nlo = uu * lo + tt * sv;
      const float nhi = uu * sv + tt * hi;
      lo = nlo; hi = nhi;
      float* tmp = wc; wc = wn; wn = tmp;
    }
    float acc = 0.f;
    for (int j = 0; j < M; ++j) acc += wc[j] * g_vals[j];
    outv = acc;
  }

  if (gid < n) out[gid] = outv;
}

extern "C" void kernel_launch(void* const* d_in, const int* in_sizes, int n_in,
                              void* d_out, int out_size, void* d_ws, size_t ws_size,
                              hipStream_t stream) {
  const float* x   = (const float*)d_in[0];
  const float* spp = (const float*)d_in[1];
  const float* vp  = (const float*)d_in[2];
  const float* Lm  = (const float*)d_in[3];
  const float* Rm  = (const float*)d_in[4];
  const int* dpt   = (const int*)d_in[5];
  float* out = (float*)d_out;
  const int n = in_sizes[0];

  hipLaunchKernelGGL(setup_kernel, dim3(1), dim3(256), 0, stream, spp, vp, Lm, Rm);
  const int blocks = (n + BT - 1) / BT;
  hipLaunchKernelGGL(fractal_fast, dim3(blocks), dim3(BT), 0, stream, x, dpt, out, n);
}